// Round 1
// baseline (466.204 us; speedup 1.0000x reference)
//
#include <hip/hip_runtime.h>
#include <cfloat>
#include <math.h>

#define B_ 8
#define C_ 256
#define H_ 128
#define W_ 128
#define N_ (H_*W_)            // 16384
#define NRAND 32
#define NHARD 96
#define NPOS 256
#define INV_TEMP (1.0f/0.07f)

// ---------------------------------------------------------------------------
// k1: normalize rgb along C and write transposed rgbT[b][n][c] (contiguous C).
// 32-pixel tiles staged in LDS (pad 257 to keep <=2-way bank aliasing).
// ---------------------------------------------------------------------------
__global__ __launch_bounds__(256) void k1_rgb_norm_T(const float* __restrict__ rgb,
                                                     float* __restrict__ rgbT) {
    __shared__ float tile[32][257];
    __shared__ float red[8][32];
    __shared__ float invn[32];
    int bi = blockIdx.x;
    int b  = bi >> 9;               // N_/32 = 512 tiles per batch
    int p0 = (bi & 511) << 5;
    int t  = threadIdx.x;
    int px = t & 31, sub = t >> 5;  // sub in [0,8)
    const float* src = rgb + (size_t)b * C_ * N_ + p0;
    float ss = 0.f;
    #pragma unroll 4
    for (int i = 0; i < 32; ++i) {
        int c = sub * 32 + i;
        float v = src[(size_t)c * N_ + px];
        tile[px][c] = v;
        ss += v * v;
    }
    red[sub][px] = ss;
    __syncthreads();
    if (t < 32) {
        float s = 0.f;
        #pragma unroll
        for (int u = 0; u < 8; ++u) s += red[u][t];
        invn[t] = 1.0f / fmaxf(sqrtf(s), 1e-12f);
    }
    __syncthreads();
    int cl = t & 31;
    #pragma unroll
    for (int j = 0; j < 4; ++j) {
        int ppx = sub * 4 + j;      // each px exactly once
        float sc = invn[ppx];
        float* dst = rgbT + ((size_t)(b * N_ + p0 + ppx)) * C_;
        #pragma unroll
        for (int u = 0; u < 8; ++u) {
            int c = u * 32 + cl;
            dst[c] = tile[ppx][c] * sc;
        }
    }
}

// ---------------------------------------------------------------------------
// k2: per 64-pixel tile: pos_sim (bilinear of rgbT dotted with dep),
// 32 rand-negative sims, per-pixel lse_base / pos_sim / max_neg.
// Thread mapping: quad per pixel (px = t>>2, g = t&3); thread g owns bilinear
// neighbor g plus rand vectors [g*8, g*8+8). Depth normalization folded into
// the final scale (all sims are linear in dep).
// ---------------------------------------------------------------------------
__global__ __launch_bounds__(256) void k2_main(
        const float* __restrict__ dep, const float* __restrict__ rgbT,
        const float* __restrict__ coords, const int* __restrict__ rand_idx,
        float* __restrict__ lse_base, float* __restrict__ pos_out,
        float* __restrict__ maxneg_out) {
    __shared__ float dep_lds[64][64];                    // [c-within-chunk][px] 16KB
    __shared__ __align__(16) float rand_lds[32][256];    // [k][c] 32KB
    __shared__ float red[4][64];
    __shared__ float invn[64];
    int bi = blockIdx.x;
    int b  = bi >> 8;               // N_/64 = 256 tiles per batch
    int p0 = (bi & 255) << 6;
    int t  = threadIdx.x;
    // stage 32 rand vectors (normalized rgb) : [k][c], c = t
    for (int k = 0; k < NRAND; ++k) {
        int idx = rand_idx[b * NRAND + k];
        rand_lds[k][t] = rgbT[((size_t)(b * N_ + idx)) * C_ + t];
    }
    int px = t >> 2, g = t & 3;
    int n  = p0 + px;
    float xf = coords[(size_t)b * 2 * N_ + n];
    float yf = coords[(size_t)b * 2 * N_ + N_ + n];
    float x0 = floorf(xf), y0 = floorf(yf);
    float wx = xf - x0, wy = yf - y0;
    int ix = (int)x0 + (g & 1);
    int iy = (int)y0 + (g >> 1);
    float wgt = ((g & 1) ? wx : 1.f - wx) * ((g & 2) ? wy : 1.f - wy);
    if (ix < 0 || ix >= W_ || iy < 0 || iy >= H_) wgt = 0.f;
    int ixc = min(max(ix, 0), W_ - 1), iyc = min(max(iy, 0), H_ - 1);
    const float* nbr  = rgbT + ((size_t)(b * N_ + iyc * W_ + ixc)) * C_;
    const float* depb = dep + (size_t)b * C_ * N_;
    float accN = 0.f, accR[8];
    #pragma unroll
    for (int j = 0; j < 8; ++j) accR[j] = 0.f;
    float ss = 0.f;
    int lane = t & 63, w = t >> 6;
    __syncthreads();                // rand staged
    for (int ch = 0; ch < 4; ++ch) {
        // stage depth chunk (64 channels x 64 px); accumulate sum of squares
        #pragma unroll
        for (int i = 0; i < 16; ++i) {
            int cc = w * 16 + i;
            int c  = ch * 64 + cc;
            float v = depb[(size_t)c * N_ + p0 + lane];
            dep_lds[cc][lane] = v;
            ss += v * v;
        }
        if (ch == 3) red[w][lane] = ss;   // complete after last staging
        __syncthreads();
        #pragma unroll 2
        for (int c4 = 0; c4 < 16; ++c4) {
            int cc = c4 * 4;
            int c  = ch * 64 + cc;
            float d0 = dep_lds[cc + 0][px];
            float d1 = dep_lds[cc + 1][px];
            float d2 = dep_lds[cc + 2][px];
            float d3 = dep_lds[cc + 3][px];
            float4 v = *(const float4*)(nbr + c);
            accN += d0 * v.x + d1 * v.y + d2 * v.z + d3 * v.w;
            #pragma unroll
            for (int j = 0; j < 8; ++j) {
                const float4 r = *(const float4*)(&rand_lds[g * 8 + j][c]);
                accR[j] += d0 * r.x + d1 * r.y + d2 * r.z + d3 * r.w;
            }
        }
        __syncthreads();
    }
    if (t < 64) {
        float s = red[0][t] + red[1][t] + red[2][t] + red[3][t];
        invn[t] = 1.0f / fmaxf(sqrtf(s), 1e-12f);
    }
    __syncthreads();
    float scale = invn[px] * INV_TEMP;
    float pp = accN * wgt;
    pp += __shfl_xor(pp, 1, 4);
    pp += __shfl_xor(pp, 2, 4);
    float pos = pp * scale;
    float r[8];
    float ml = -FLT_MAX;
    #pragma unroll
    for (int j = 0; j < 8; ++j) { r[j] = accR[j] * scale; ml = fmaxf(ml, r[j]); }
    ml = fmaxf(ml, __shfl_xor(ml, 1, 4));
    ml = fmaxf(ml, __shfl_xor(ml, 2, 4));
    float mneg = ml;                        // max over 32 rand negatives
    float mall = fmaxf(mneg, pos);
    float se = 0.f;
    #pragma unroll
    for (int j = 0; j < 8; ++j) se += expf(r[j] - mall);
    se += __shfl_xor(se, 1, 4);
    se += __shfl_xor(se, 2, 4);
    if (g == 0) {
        float lse = mall + logf(se + expf(pos - mall));
        size_t o = (size_t)b * N_ + n;
        lse_base[o]   = lse;
        pos_out[o]    = pos;
        maxneg_out[o] = mneg;
    }
}

// ---------------------------------------------------------------------------
// k3: hard negatives. One block per (b, grid-point p): 96 hard sims,
// logsumexp + max over the 96.
// ---------------------------------------------------------------------------
__global__ __launch_bounds__(128) void k3_hard(
        const float* __restrict__ dep, const float* __restrict__ rgbT,
        const float* __restrict__ coords, const int* __restrict__ hoffu,
        const int* __restrict__ hoffv, float* __restrict__ lse_hard,
        float* __restrict__ max_hard) {
    __shared__ __align__(16) float dv[256];
    __shared__ float sred[2], sm_[2], ss_[2];
    int bp = blockIdx.x;
    int b = bp >> 8, p = bp & 255;
    int gy = (p >> 4) * 8, gx = (p & 15) * 8;
    int n  = gy * W_ + gx;
    int t  = threadIdx.x;
    const float* depb = dep + (size_t)b * C_ * N_;
    float v0 = depb[(size_t)t * N_ + n];
    float v1 = depb[(size_t)(t + 128) * N_ + n];
    dv[t] = v0; dv[t + 128] = v1;
    float ssq = v0 * v0 + v1 * v1;
    #pragma unroll
    for (int o = 32; o > 0; o >>= 1) ssq += __shfl_down(ssq, o, 64);
    int wid = t >> 6;
    if ((t & 63) == 0) sred[wid] = ssq;
    __syncthreads();                 // also covers dv[] visibility
    float inv_n = 1.0f / fmaxf(sqrtf(sred[0] + sred[1]), 1e-12f);
    float pu = coords[(size_t)b * 2 * N_ + n];
    float pv = coords[(size_t)b * 2 * N_ + N_ + n];
    int iu = (int)fminf(fmaxf(pu, 0.f), (float)(W_ - 1));
    int iv = (int)fminf(fmaxf(pv, 0.f), (float)(H_ - 1));
    float sim = -FLT_MAX;
    if (t < NHARD) {
        int ou = hoffu[((size_t)b * NHARD + t) * NPOS + p];
        int ov = hoffv[((size_t)b * NHARD + t) * NPOS + p];
        if (ou == 0 && ov == 0) ou = 1;
        int hu = min(max(iu + ou, 0), W_ - 1);
        int hv = min(max(iv + ov, 0), H_ - 1);
        const float* hvec = rgbT + ((size_t)(b * N_ + hv * W_ + hu)) * C_;
        float acc = 0.f;
        #pragma unroll 4
        for (int c4 = 0; c4 < 64; ++c4) {
            float4 d  = *(const float4*)(&dv[c4 * 4]);
            float4 rv = *(const float4*)(hvec + c4 * 4);
            acc += d.x * rv.x + d.y * rv.y + d.z * rv.z + d.w * rv.w;
        }
        sim = acc * inv_n * INV_TEMP;
    }
    float m = sim;
    #pragma unroll
    for (int o = 32; o > 0; o >>= 1) m = fmaxf(m, __shfl_down(m, o, 64));
    if ((t & 63) == 0) sm_[wid] = m;
    __syncthreads();
    float mm = fmaxf(sm_[0], sm_[1]);
    float e = (t < NHARD) ? expf(sim - mm) : 0.f;
    #pragma unroll
    for (int o = 32; o > 0; o >>= 1) e += __shfl_down(e, o, 64);
    if ((t & 63) == 0) ss_[wid] = e;
    __syncthreads();
    if (t == 0) {
        lse_hard[bp] = mm + logf(ss_[0] + ss_[1]);
        max_hard[bp] = mm;
    }
}

// ---------------------------------------------------------------------------
// k4: masked reduction over all pixels (with grid-point hard fix-up).
// ---------------------------------------------------------------------------
__global__ __launch_bounds__(256) void k4_reduce(
        const float* __restrict__ lse_base, const float* __restrict__ pos_sim,
        const float* __restrict__ max_neg, const float* __restrict__ mask,
        const float* __restrict__ lse_hard, const float* __restrict__ max_hard,
        float* __restrict__ acc) {
    int i = blockIdx.x * 256 + threadIdx.x;     // < B_*N_
    float l  = lse_base[i], ps = pos_sim[i], mn = max_neg[i], mk = mask[i];
    int b = i >> 14;
    int n = i & (N_ - 1);
    int y = n >> 7, x = n & 127;
    if (((y & 7) | (x & 7)) == 0) {
        int p = ((y >> 3) << 4) + (x >> 3);
        float lh = lse_hard[(b << 8) + p];
        float mh = max_hard[(b << 8) + p];
        float m = fmaxf(l, lh);
        l  = m + logf(expf(l - m) + expf(lh - m));
        mn = fmaxf(mn, mh);
    }
    float s0 = (l - ps) * mk;
    float s1 = (ps > mn && mk > 0.5f) ? 1.f : 0.f;
    float s2 = mk;
    #pragma unroll
    for (int o = 32; o > 0; o >>= 1) {
        s0 += __shfl_down(s0, o, 64);
        s1 += __shfl_down(s1, o, 64);
        s2 += __shfl_down(s2, o, 64);
    }
    __shared__ float r0[4], r1[4], r2[4];
    int wid = threadIdx.x >> 6;
    if ((threadIdx.x & 63) == 0) { r0[wid] = s0; r1[wid] = s1; r2[wid] = s2; }
    __syncthreads();
    if (threadIdx.x == 0) {
        atomicAdd(&acc[0], r0[0] + r0[1] + r0[2] + r0[3]);
        atomicAdd(&acc[1], r1[0] + r1[1] + r1[2] + r1[3]);
        atomicAdd(&acc[2], r2[0] + r2[1] + r2[2] + r2[3]);
    }
}

__global__ void k5_final(const float* __restrict__ acc, float* __restrict__ out) {
    if (threadIdx.x == 0) {
        float denom = fmaxf(acc[2], 1.0f);
        out[0] = acc[0] / denom;
        out[1] = acc[1] / denom * 100.0f;
    }
}

extern "C" void kernel_launch(void* const* d_in, const int* in_sizes, int n_in,
                              void* d_out, int out_size, void* d_ws, size_t ws_size,
                              hipStream_t stream) {
    const float* rgb     = (const float*)d_in[0];
    const float* dep     = (const float*)d_in[1];
    const float* coords  = (const float*)d_in[2];
    const float* mask    = (const float*)d_in[3];
    const int*   rand_i  = (const int*)d_in[4];
    const int*   hoffu   = (const int*)d_in[5];
    const int*   hoffv   = (const int*)d_in[6];
    float* out = (float*)d_out;
    char*  ws  = (char*)d_ws;

    const size_t RGBT_B = (size_t)B_ * N_ * C_ * 4;      // 134217728
    const size_t PIX_B  = (size_t)B_ * N_ * 4;           // 524288
    float* rgbT     = (float*)ws;
    float* lse_base = (float*)(ws + RGBT_B);
    float* pos_sim  = (float*)(ws + RGBT_B + PIX_B);
    float* max_neg  = (float*)(ws + RGBT_B + 2 * PIX_B);
    float* lse_hard = (float*)(ws + RGBT_B + 3 * PIX_B);
    float* max_hard = (float*)(ws + RGBT_B + 3 * PIX_B + 8192);
    float* acc      = (float*)(ws + RGBT_B + 3 * PIX_B + 2 * 8192);

    hipMemsetAsync(acc, 0, 16, stream);
    k1_rgb_norm_T<<<B_ * (N_ / 32), 256, 0, stream>>>(rgb, rgbT);
    k2_main<<<B_ * (N_ / 64), 256, 0, stream>>>(dep, rgbT, coords, rand_i,
                                                lse_base, pos_sim, max_neg);
    k3_hard<<<B_ * NPOS, 128, 0, stream>>>(dep, rgbT, coords, hoffu, hoffv,
                                           lse_hard, max_hard);
    k4_reduce<<<(B_ * N_) / 256, 256, 0, stream>>>(lse_base, pos_sim, max_neg,
                                                   mask, lse_hard, max_hard, acc);
    k5_final<<<1, 64, 0, stream>>>(acc, out);
}

// Round 2
// 414.885 us; speedup vs baseline: 1.1237x; 1.1237x over previous
//
#include <hip/hip_runtime.h>
#include <cfloat>
#include <math.h>

#define B_ 8
#define C_ 256
#define C2_ (C_/2)            // uints (bf16 pairs) per pixel
#define H_ 128
#define W_ 128
#define N_ (H_*W_)            // 16384
#define NRAND 32
#define NHARD 96
#define NPOS 256
#define INV_TEMP (1.0f/0.07f)

__device__ __forceinline__ unsigned bf16rne(float x) {
    unsigned u = __float_as_uint(x);
    return (u + 0x7FFFu + ((u >> 16) & 1u)) >> 16;
}
__device__ __forceinline__ float blo(unsigned w) { return __uint_as_float(w << 16); }
__device__ __forceinline__ float bhi(unsigned w) { return __uint_as_float(w & 0xFFFF0000u); }

// ---------------------------------------------------------------------------
// k1: normalize rgb along C, write transposed bf16 rgbT[b][n][c] (packed u32).
// 64-px tile per block. float2 global reads; LDS transpose (pad 67);
// fully coalesced 256B packed stores.
// ---------------------------------------------------------------------------
__global__ __launch_bounds__(256) void k1_rgb_norm_T(const float* __restrict__ rgb,
                                                     unsigned* __restrict__ rgbT) {
    __shared__ float tile[C_][67];
    __shared__ float redx[8][32], redy[8][32];
    __shared__ float invn[64];
    int bi = blockIdx.x;
    int b  = bi >> 8;                 // 256 tiles per batch
    int p0 = (bi & 255) << 6;
    int t  = threadIdx.x;
    int pxh = t & 31;                 // float2 pixel-pair index
    int cg  = t >> 5;                 // 0..7
    const float2* src2 = (const float2*)(rgb + (size_t)b * C_ * N_);
    float ssx = 0.f, ssy = 0.f;
    #pragma unroll 4
    for (int p = 0; p < 32; ++p) {
        int c = p * 8 + cg;
        float2 v = src2[(size_t)c * (N_ / 2) + (p0 >> 1) + pxh];
        tile[c][2 * pxh]     = v.x;
        tile[c][2 * pxh + 1] = v.y;
        ssx += v.x * v.x;
        ssy += v.y * v.y;
    }
    redx[cg][pxh] = ssx; redy[cg][pxh] = ssy;
    __syncthreads();
    if (t < 32) {
        float sx = 0.f, sy = 0.f;
        #pragma unroll
        for (int g2 = 0; g2 < 8; ++g2) { sx += redx[g2][t]; sy += redy[g2][t]; }
        invn[2 * t]     = 1.0f / fmaxf(sqrtf(sx), 1e-12f);
        invn[2 * t + 1] = 1.0f / fmaxf(sqrtf(sy), 1e-12f);
    }
    __syncthreads();
    unsigned* dst = rgbT + (size_t)(b * N_ + p0) * C2_;
    int u  = t & 127;                 // uint (channel-pair) index
    int ph = t >> 7;
    #pragma unroll 4
    for (int it = 0; it < 32; ++it) {
        int px = ph + 2 * it;
        float sc = invn[px];
        unsigned pa = bf16rne(tile[2 * u][px] * sc);
        unsigned pb = bf16rne(tile[2 * u + 1][px] * sc);
        dst[(size_t)px * C2_ + u] = pa | (pb << 16);
    }
}

// ---------------------------------------------------------------------------
// k2: per 64-pixel tile: pos_sim (bilinear gather of bf16 rgbT vs fp32 dep),
// 32 rand-negative sims, per-pixel lse_base / pos_sim / max_neg.
// Quad per pixel (px=t>>2, g=t&3): thread g owns bilinear neighbor g + rand
// vectors [g*8,g*8+8). Channel loop rotated by 2*g c4-steps so the 4 distinct
// rand_lds addresses per wave land on banks {0,8,16,24} (conflict-free).
// ---------------------------------------------------------------------------
__global__ __launch_bounds__(256) void k2_main(
        const float* __restrict__ dep, const unsigned* __restrict__ rgbT,
        const float* __restrict__ coords, const int* __restrict__ rand_idx,
        float* __restrict__ lse_base, float* __restrict__ pos_out,
        float* __restrict__ maxneg_out) {
    __shared__ float dep_lds[64][64];                    // [c-within-chunk][px]
    __shared__ __align__(16) float rand_lds[32][256];    // [k][c] fp32 (unpacked)
    __shared__ float red[4][64];
    __shared__ float invn[64];
    int bi = blockIdx.x;
    int b  = bi >> 8;
    int p0 = (bi & 255) << 6;
    int t  = threadIdx.x;
    // stage 32 rand vectors: bf16 gather -> fp32 LDS
    {
        int u  = t & 127, kh = t >> 7;
        #pragma unroll 4
        for (int pass = 0; pass < 16; ++pass) {
            int k = kh + 2 * pass;
            int idx = rand_idx[b * NRAND + k];
            unsigned w = rgbT[(size_t)(b * N_ + idx) * C2_ + u];
            rand_lds[k][2 * u]     = blo(w);
            rand_lds[k][2 * u + 1] = bhi(w);
        }
    }
    int px = t >> 2, g = t & 3;
    int n  = p0 + px;
    float xf = coords[(size_t)b * 2 * N_ + n];
    float yf = coords[(size_t)b * 2 * N_ + N_ + n];
    float x0 = floorf(xf), y0 = floorf(yf);
    float wx = xf - x0, wy = yf - y0;
    int ix = (int)x0 + (g & 1);
    int iy = (int)y0 + (g >> 1);
    float wgt = ((g & 1) ? wx : 1.f - wx) * ((g & 2) ? wy : 1.f - wy);
    if (ix < 0 || ix >= W_ || iy < 0 || iy >= H_) wgt = 0.f;
    int ixc = min(max(ix, 0), W_ - 1), iyc = min(max(iy, 0), H_ - 1);
    const unsigned* nbr = rgbT + (size_t)(b * N_ + iyc * W_ + ixc) * C2_;
    const float* depb = dep + (size_t)b * C_ * N_;
    float accN = 0.f, accR[8];
    #pragma unroll
    for (int j = 0; j < 8; ++j) accR[j] = 0.f;
    float ss = 0.f;
    int lane = t & 63, w = t >> 6;
    __syncthreads();                // rand staged
    for (int ch = 0; ch < 4; ++ch) {
        #pragma unroll
        for (int i = 0; i < 16; ++i) {
            int cc = w * 16 + i;
            float v = depb[(size_t)(ch * 64 + cc) * N_ + p0 + lane];
            dep_lds[cc][lane] = v;
            ss += v * v;
        }
        if (ch == 3) red[w][lane] = ss;
        __syncthreads();
        #pragma unroll
        for (int c4i = 0; c4i < 16; ++c4i) {
            int c4 = (c4i + 2 * g) & 15;     // g-rotation: banks {0,8,16,24}
            int cc = c4 * 4;
            int c  = ch * 64 + cc;
            float d0 = dep_lds[cc + 0][px];
            float d1 = dep_lds[cc + 1][px];
            float d2 = dep_lds[cc + 2][px];
            float d3 = dep_lds[cc + 3][px];
            uint2 q = *(const uint2*)(nbr + (c >> 1));
            accN += d0 * blo(q.x) + d1 * bhi(q.x) + d2 * blo(q.y) + d3 * bhi(q.y);
            #pragma unroll
            for (int j = 0; j < 8; ++j) {
                const float4 r = *(const float4*)(&rand_lds[g * 8 + j][c]);
                accR[j] += d0 * r.x + d1 * r.y + d2 * r.z + d3 * r.w;
            }
        }
        __syncthreads();
    }
    if (t < 64) {
        float s = red[0][t] + red[1][t] + red[2][t] + red[3][t];
        invn[t] = 1.0f / fmaxf(sqrtf(s), 1e-12f);
    }
    __syncthreads();
    float scale = invn[px] * INV_TEMP;
    float pp = accN * wgt;
    pp += __shfl_xor(pp, 1, 4);
    pp += __shfl_xor(pp, 2, 4);
    float pos = pp * scale;
    float r[8];
    float ml = -FLT_MAX;
    #pragma unroll
    for (int j = 0; j < 8; ++j) { r[j] = accR[j] * scale; ml = fmaxf(ml, r[j]); }
    ml = fmaxf(ml, __shfl_xor(ml, 1, 4));
    ml = fmaxf(ml, __shfl_xor(ml, 2, 4));
    float mneg = ml;
    float mall = fmaxf(mneg, pos);
    float se = 0.f;
    #pragma unroll
    for (int j = 0; j < 8; ++j) se += expf(r[j] - mall);
    se += __shfl_xor(se, 1, 4);
    se += __shfl_xor(se, 2, 4);
    if (g == 0) {
        float lse = mall + logf(se + expf(pos - mall));
        size_t o = (size_t)b * N_ + n;
        lse_base[o]   = lse;
        pos_out[o]    = pos;
        maxneg_out[o] = mneg;
    }
}

// ---------------------------------------------------------------------------
// k3: hard negatives. One block per (b, grid-point p): 96 hard sims,
// logsumexp + max. rgbT gathers are bf16 uint4 (8 ch / 16B).
// ---------------------------------------------------------------------------
__global__ __launch_bounds__(128) void k3_hard(
        const float* __restrict__ dep, const unsigned* __restrict__ rgbT,
        const float* __restrict__ coords, const int* __restrict__ hoffu,
        const int* __restrict__ hoffv, float* __restrict__ lse_hard,
        float* __restrict__ max_hard) {
    __shared__ __align__(16) float dv[256];
    __shared__ float sred[2], sm_[2], ss_[2];
    int bp = blockIdx.x;
    int b = bp >> 8, p = bp & 255;
    int gy = (p >> 4) * 8, gx = (p & 15) * 8;
    int n  = gy * W_ + gx;
    int t  = threadIdx.x;
    const float* depb = dep + (size_t)b * C_ * N_;
    float v0 = depb[(size_t)t * N_ + n];
    float v1 = depb[(size_t)(t + 128) * N_ + n];
    dv[t] = v0; dv[t + 128] = v1;
    float ssq = v0 * v0 + v1 * v1;
    #pragma unroll
    for (int o = 32; o > 0; o >>= 1) ssq += __shfl_down(ssq, o, 64);
    int wid = t >> 6;
    if ((t & 63) == 0) sred[wid] = ssq;
    __syncthreads();
    float inv_n = 1.0f / fmaxf(sqrtf(sred[0] + sred[1]), 1e-12f);
    float pu = coords[(size_t)b * 2 * N_ + n];
    float pv = coords[(size_t)b * 2 * N_ + N_ + n];
    int iu = (int)fminf(fmaxf(pu, 0.f), (float)(W_ - 1));
    int iv = (int)fminf(fmaxf(pv, 0.f), (float)(H_ - 1));
    float sim = -FLT_MAX;
    if (t < NHARD) {
        int ou = hoffu[((size_t)b * NHARD + t) * NPOS + p];
        int ov = hoffv[((size_t)b * NHARD + t) * NPOS + p];
        if (ou == 0 && ov == 0) ou = 1;
        int hu = min(max(iu + ou, 0), W_ - 1);
        int hv = min(max(iv + ov, 0), H_ - 1);
        const uint4* hvec = (const uint4*)(rgbT + (size_t)(b * N_ + hv * W_ + hu) * C2_);
        float acc = 0.f;
        #pragma unroll 4
        for (int c8 = 0; c8 < 32; ++c8) {
            uint4 q = hvec[c8];
            float4 d0 = *(const float4*)(&dv[c8 * 8]);
            float4 d1 = *(const float4*)(&dv[c8 * 8 + 4]);
            acc += d0.x * blo(q.x) + d0.y * bhi(q.x)
                 + d0.z * blo(q.y) + d0.w * bhi(q.y)
                 + d1.x * blo(q.z) + d1.y * bhi(q.z)
                 + d1.z * blo(q.w) + d1.w * bhi(q.w);
        }
        sim = acc * inv_n * INV_TEMP;
    }
    float m = sim;
    #pragma unroll
    for (int o = 32; o > 0; o >>= 1) m = fmaxf(m, __shfl_down(m, o, 64));
    if ((t & 63) == 0) sm_[wid] = m;
    __syncthreads();
    float mm = fmaxf(sm_[0], sm_[1]);
    float e = (t < NHARD) ? expf(sim - mm) : 0.f;
    #pragma unroll
    for (int o = 32; o > 0; o >>= 1) e += __shfl_down(e, o, 64);
    if ((t & 63) == 0) ss_[wid] = e;
    __syncthreads();
    if (t == 0) {
        lse_hard[bp] = mm + logf(ss_[0] + ss_[1]);
        max_hard[bp] = mm;
    }
}

// ---------------------------------------------------------------------------
// k4: masked reduction over all pixels (with grid-point hard fix-up).
// ---------------------------------------------------------------------------
__global__ __launch_bounds__(256) void k4_reduce(
        const float* __restrict__ lse_base, const float* __restrict__ pos_sim,
        const float* __restrict__ max_neg, const float* __restrict__ mask,
        const float* __restrict__ lse_hard, const float* __restrict__ max_hard,
        float* __restrict__ acc) {
    int i = blockIdx.x * 256 + threadIdx.x;
    float l  = lse_base[i], ps = pos_sim[i], mn = max_neg[i], mk = mask[i];
    int b = i >> 14;
    int n = i & (N_ - 1);
    int y = n >> 7, x = n & 127;
    if (((y & 7) | (x & 7)) == 0) {
        int p = ((y >> 3) << 4) + (x >> 3);
        float lh = lse_hard[(b << 8) + p];
        float mh = max_hard[(b << 8) + p];
        float m = fmaxf(l, lh);
        l  = m + logf(expf(l - m) + expf(lh - m));
        mn = fmaxf(mn, mh);
    }
    float s0 = (l - ps) * mk;
    float s1 = (ps > mn && mk > 0.5f) ? 1.f : 0.f;
    float s2 = mk;
    #pragma unroll
    for (int o = 32; o > 0; o >>= 1) {
        s0 += __shfl_down(s0, o, 64);
        s1 += __shfl_down(s1, o, 64);
        s2 += __shfl_down(s2, o, 64);
    }
    __shared__ float r0[4], r1[4], r2[4];
    int wid = threadIdx.x >> 6;
    if ((threadIdx.x & 63) == 0) { r0[wid] = s0; r1[wid] = s1; r2[wid] = s2; }
    __syncthreads();
    if (threadIdx.x == 0) {
        atomicAdd(&acc[0], r0[0] + r0[1] + r0[2] + r0[3]);
        atomicAdd(&acc[1], r1[0] + r1[1] + r1[2] + r1[3]);
        atomicAdd(&acc[2], r2[0] + r2[1] + r2[2] + r2[3]);
    }
}

__global__ void k5_final(const float* __restrict__ acc, float* __restrict__ out) {
    if (threadIdx.x == 0) {
        float denom = fmaxf(acc[2], 1.0f);
        out[0] = acc[0] / denom;
        out[1] = acc[1] / denom * 100.0f;
    }
}

extern "C" void kernel_launch(void* const* d_in, const int* in_sizes, int n_in,
                              void* d_out, int out_size, void* d_ws, size_t ws_size,
                              hipStream_t stream) {
    const float* rgb     = (const float*)d_in[0];
    const float* dep     = (const float*)d_in[1];
    const float* coords  = (const float*)d_in[2];
    const float* mask    = (const float*)d_in[3];
    const int*   rand_i  = (const int*)d_in[4];
    const int*   hoffu   = (const int*)d_in[5];
    const int*   hoffv   = (const int*)d_in[6];
    float* out = (float*)d_out;
    char*  ws  = (char*)d_ws;

    const size_t RGBT_B = (size_t)B_ * N_ * C_ * 2;      // bf16: 67108864 B
    const size_t PIX_B  = (size_t)B_ * N_ * 4;           // 524288 B
    unsigned* rgbT  = (unsigned*)ws;
    float* lse_base = (float*)(ws + RGBT_B);
    float* pos_sim  = (float*)(ws + RGBT_B + PIX_B);
    float* max_neg  = (float*)(ws + RGBT_B + 2 * PIX_B);
    float* lse_hard = (float*)(ws + RGBT_B + 3 * PIX_B);
    float* max_hard = (float*)(ws + RGBT_B + 3 * PIX_B + 8192);
    float* acc      = (float*)(ws + RGBT_B + 3 * PIX_B + 2 * 8192);

    hipMemsetAsync(acc, 0, 16, stream);
    k1_rgb_norm_T<<<B_ * (N_ / 64), 256, 0, stream>>>(rgb, rgbT);
    k2_main<<<B_ * (N_ / 64), 256, 0, stream>>>(dep, rgbT, coords, rand_i,
                                                lse_base, pos_sim, max_neg);
    k3_hard<<<B_ * NPOS, 128, 0, stream>>>(dep, rgbT, coords, hoffu, hoffv,
                                           lse_hard, max_hard);
    k4_reduce<<<(B_ * N_) / 256, 256, 0, stream>>>(lse_base, pos_sim, max_neg,
                                                   mask, lse_hard, max_hard, acc);
    k5_final<<<1, 64, 0, stream>>>(acc, out);
}